// Round 10
// baseline (198.128 us; speedup 1.0000x reference)
//
#include <hip/hip_runtime.h>
#include <hip/hip_bf16.h>

#define NB 8
#define NC 256
#define NL 2048
#define ND 128
#define NROWS (NB * NL)                   // 16384 Q rows
#define QKV_ELEMS ((size_t)NB * NL * ND)  // 2,097,152
#define W_ELEMS (ND * NC)                 // 32,768
#define XS_STRIDE 264                     // 256 + 8 shorts pad: 16B-aligned rows
#define NSPLIT 4

typedef __attribute__((ext_vector_type(8))) short bf16x8;
typedef __attribute__((ext_vector_type(4))) float f32x4;
typedef __attribute__((ext_vector_type(16))) float f32x16;

__device__ __forceinline__ unsigned short f2bf(float f) {
    union { float f; unsigned u; } v; v.f = f;
    unsigned r = v.u + 0x7fffu + ((v.u >> 16) & 1u);
    return (unsigned short)(r >> 16);
}

// packed RNE f32x2 -> bf16x2 (v_cvt_pk_bf16_f32 on gfx950)
__device__ __forceinline__ unsigned f2bf_pk(float a, float b) {
    __hip_bfloat162 h = __float22bfloat162_rn(make_float2(a, b));
    return *reinterpret_cast<unsigned*>(&h);
}

// async global->LDS, 16 B per lane; LDS dest = uniform base + lane*16
__device__ __forceinline__ void load_lds16(const unsigned short* g, unsigned short* l) {
    __builtin_amdgcn_global_load_lds((const __attribute__((address_space(1))) unsigned int*)g,
                                     (__attribute__((address_space(3))) unsigned int*)l, 16, 0, 0);
}

// cast Wq|Wk|Wv -> contiguous bf16 buffer [3][D][C]
__global__ void cast_w3(const float* __restrict__ wq, const float* __restrict__ wk,
                        const float* __restrict__ wv, unsigned short* __restrict__ dst) {
    int i = blockIdx.x * blockDim.x + threadIdx.x;
    if (i >= 3 * W_ELEMS) return;
    int sel = i / W_ELEMS, off = i - sel * W_ELEMS;
    const float* s = (sel == 0) ? wq : (sel == 1) ? wk : wv;
    dst[i] = f2bf(s[off]);
}

// Fused transpose+cast+projection. Reads x [b][C][L] f32 directly.
// blockIdx.x: b*32 + l-tile (64 l's). blockIdx.y: 0 = Q (xi), 1 = K (xo), 2 = V (xo).
__global__ __launch_bounds__(256, 4) void proj_direct(const float* __restrict__ xi,
                                                      const float* __restrict__ xo,
                                                      const unsigned short* __restrict__ Wall,
                                                      const float* __restrict__ bq,
                                                      const float* __restrict__ bk,
                                                      const float* __restrict__ bv,
                                                      unsigned short* __restrict__ Qb,
                                                      unsigned short* __restrict__ Kb,
                                                      unsigned short* __restrict__ Vtb) {
    __shared__ unsigned short xs[64 * XS_STRIDE];  // x^T tile [64 l][256 c] bf16, 33 KB
    int b = blockIdx.x >> 5, lt = blockIdx.x & 31, l0 = lt * 64;
    int y = blockIdx.y;
    int wave = threadIdx.x >> 6, lane = threadIdx.x & 63;
    int ln = lane & 15, quad = lane >> 4;

    // ---- stage: xs[l][c] = bf16(x[c][l0+l]); float4 loads, packed converts ----
    const float* xsrc = (y == 0 ? xi : xo) + (size_t)b * NC * NL + l0;
    int l4 = (lane & 15) * 4;
    int cr0 = wave * 4 + (lane >> 4);
    #pragma unroll
    for (int g = 0; g < 4; g++) {
        float4 r[4];
        #pragma unroll
        for (int gi = 0; gi < 4; gi++) {
            int c = cr0 + (g * 4 + gi) * 16;
            r[gi] = *reinterpret_cast<const float4*>(xsrc + (size_t)c * NL + l4);
        }
        #pragma unroll
        for (int gi = 0; gi < 4; gi++) {
            int c = cr0 + (g * 4 + gi) * 16;
            unsigned pk0 = f2bf_pk(r[gi].x, r[gi].y);
            unsigned pk1 = f2bf_pk(r[gi].z, r[gi].w);
            xs[(l4 + 0) * XS_STRIDE + c] = (unsigned short)pk0;
            xs[(l4 + 1) * XS_STRIDE + c] = (unsigned short)(pk0 >> 16);
            xs[(l4 + 2) * XS_STRIDE + c] = (unsigned short)pk1;
            xs[(l4 + 3) * XS_STRIDE + c] = (unsigned short)(pk1 >> 16);
        }
    }
    __syncthreads();

    if (y < 2) {
        // ---- Q or K: out[l][d] = sum_c xs[l][c] * W[d][c] + bias[d], [B,L,D] ----
        const unsigned short* Wb = Wall + (size_t)y * W_ELEMS;
        const float* bias = y ? bk : bq;
        unsigned short* out = y ? Kb : Qb;
        int m0w = wave * 16;
        f32x4 acc[8] = {};
        #pragma unroll
        for (int s = 0; s < 8; s++) {
            bf16x8 af = *reinterpret_cast<const bf16x8*>(xs + (m0w + ln) * XS_STRIDE + s * 32 + quad * 8);
            #pragma unroll
            for (int t = 0; t < 8; t++) {
                bf16x8 bfr = *reinterpret_cast<const bf16x8*>(Wb + (size_t)(t * 16 + ln) * NC + s * 32 + quad * 8);
                acc[t] = __builtin_amdgcn_mfma_f32_16x16x32_bf16(af, bfr, acc[t], 0, 0, 0);
            }
        }
        #pragma unroll
        for (int t = 0; t < 8; t++) {
            int col = t * 16 + ln;
            float bi = bias[col];
            unsigned pk0 = f2bf_pk(acc[t][0] + bi, acc[t][1] + bi);
            unsigned pk1 = f2bf_pk(acc[t][2] + bi, acc[t][3] + bi);
            size_t base = (size_t)(b * NL + l0 + m0w + quad * 4) * ND + col;
            out[base + 0 * ND] = (unsigned short)pk0;
            out[base + 1 * ND] = (unsigned short)(pk0 >> 16);
            out[base + 2 * ND] = (unsigned short)pk1;
            out[base + 3 * ND] = (unsigned short)(pk1 >> 16);
        }
    } else {
        // ---- V: vt[d][l] = sum_c W[d][c]*xs[l][c] + bv[d], [B,D,L] ----
        const unsigned short* Wb = Wall + 2 * (size_t)W_ELEMS;
        f32x4 acc[2][4] = {};
        #pragma unroll
        for (int s = 0; s < 8; s++) {
            bf16x8 wf0 = *reinterpret_cast<const bf16x8*>(Wb + (size_t)(wave * 32 + ln) * NC + s * 32 + quad * 8);
            bf16x8 wf1 = *reinterpret_cast<const bf16x8*>(Wb + (size_t)(wave * 32 + 16 + ln) * NC + s * 32 + quad * 8);
            #pragma unroll
            for (int t = 0; t < 4; t++) {
                bf16x8 xb = *reinterpret_cast<const bf16x8*>(xs + (t * 16 + ln) * XS_STRIDE + s * 32 + quad * 8);
                acc[0][t] = __builtin_amdgcn_mfma_f32_16x16x32_bf16(wf0, xb, acc[0][t], 0, 0, 0);
                acc[1][t] = __builtin_amdgcn_mfma_f32_16x16x32_bf16(wf1, xb, acc[1][t], 0, 0, 0);
            }
        }
        #pragma unroll
        for (int u = 0; u < 2; u++)
            #pragma unroll
            for (int t = 0; t < 4; t++)
                #pragma unroll
                for (int r = 0; r < 4; r++) {
                    int d = wave * 32 + u * 16 + quad * 4 + r;
                    Vtb[(size_t)(b * ND + d) * NL + l0 + t * 16 + ln] = f2bf(acc[u][t][r] + bv[d]);
                }
    }
}

// split-KV flash attention, 32x32 MFMA, 128-q blocks, fixed-M softmax, double-buffered K/V,
// FUSED last-block merge: the 4 split blocks of a (b,qt) group coordinate via a device-scope
// atomic counter; the last arriver sums the 4 partials and writes normalized output.
__global__ __launch_bounds__(256, 2) void flash_attn_split(const unsigned short* __restrict__ Q,
                                                           const unsigned short* __restrict__ K,
                                                           const unsigned short* __restrict__ Vt,
                                                           float* __restrict__ Opart,
                                                           float* __restrict__ lbuf,
                                                           int* __restrict__ cnt,
                                                           float* __restrict__ out,
                                                           int kvlen) {
    __shared__ unsigned short kbuf[2][64 * 128];
    __shared__ unsigned short vbuf[2][128 * 64];
    __shared__ unsigned short pbuf[4][32 * 64];
    __shared__ int s_last;
    int b = blockIdx.x >> 4, qt = blockIdx.x & 15;
    int sp = blockIdx.y;
    int kv0 = sp * kvlen;
    int wave = threadIdx.x >> 6, lane = threadIdx.x & 63;
    int l31 = lane & 31, h = lane >> 5;
    int m0 = qt * 128 + wave * 32;
    const float scale = 0.08838834764831845f * 1.4426950408889634f;  // 1/sqrt(128) * log2(e)

    bf16x8 qf[8];
    const unsigned short* qrow = Q + (size_t)(b * NL + m0 + l31) * ND + h * 8;
    #pragma unroll
    for (int s = 0; s < 8; s++) qf[s] = *reinterpret_cast<const bf16x8*>(qrow + s * 16);

    float lsum = 0.f;
    f32x16 o_acc[4] = {};

    unsigned short* pw = pbuf[wave];
    const unsigned short* kg = K + (size_t)b * NL * ND;
    const unsigned short* vg = Vt + (size_t)b * ND * NL;

    int krt = wave * 16 + (lane >> 4);
    int kjs = (lane & 15);
    int vdt = wave * 32 + (lane >> 3);
    int vjs = (lane & 7);

    // ---- prefetch tile 0 into buffer 0 ----
    {
        int kt = kv0;
        #pragma unroll
        for (int i = 0; i < 4; i++) {
            int rt = krt + i * 4;
            load_lds16(kg + (size_t)(kt + rt) * ND + (kjs ^ (rt & 15)) * 8, kbuf[0] + (wave * 16 + i * 4) * 128);
        }
        #pragma unroll
        for (int i = 0; i < 4; i++) {
            int dt = vdt + i * 8;
            load_lds16(vg + (size_t)dt * NL + kt + (vjs ^ (dt & 7)) * 8, vbuf[0] + (wave * 32 + i * 8) * 64);
        }
    }

    int niter = kvlen >> 6;
    for (int it = 0; it < niter; it++) {
        int cur = it & 1;
        __syncthreads();  // vmcnt drain + barrier: buffer `cur` ready, `cur^1` free

        if (it + 1 < niter) {
            int kt = kv0 + (it + 1) * 64;
            int nxt = cur ^ 1;
            #pragma unroll
            for (int i = 0; i < 4; i++) {
                int rt = krt + i * 4;
                load_lds16(kg + (size_t)(kt + rt) * ND + (kjs ^ (rt & 15)) * 8, kbuf[nxt] + (wave * 16 + i * 4) * 128);
            }
            #pragma unroll
            for (int i = 0; i < 4; i++) {
                int dt = vdt + i * 8;
                load_lds16(vg + (size_t)dt * NL + kt + (vjs ^ (dt & 7)) * 8, vbuf[nxt] + (wave * 32 + i * 8) * 64);
            }
        }
        const unsigned short* kb = kbuf[cur];
        const unsigned short* vb = vbuf[cur];

        // ---- S^T = K Q^T ----
        f32x16 sacc[2] = {};
        #pragma unroll
        for (int tt = 0; tt < 2; tt++) {
            const unsigned short* krow_p = kb + (tt * 32 + l31) * 128;
            #pragma unroll
            for (int s = 0; s < 8; s++) {
                bf16x8 kf = *reinterpret_cast<const bf16x8*>(krow_p + (((s * 2 + h) ^ (lane & 15)) << 3));
                sacc[tt] = __builtin_amdgcn_mfma_f32_32x32x16_bf16(kf, qf[s], sacc[tt], 0, 0, 0);
            }
        }
        // ---- fixed-M softmax + packed P^T write ----
        #pragma unroll
        for (int tt = 0; tt < 2; tt++) {
            #pragma unroll
            for (int g = 0; g < 4; g++) {
                float p0 = __builtin_exp2f(sacc[tt][g * 4 + 0] * scale);
                float p1 = __builtin_exp2f(sacc[tt][g * 4 + 1] * scale);
                float p2 = __builtin_exp2f(sacc[tt][g * 4 + 2] * scale);
                float p3 = __builtin_exp2f(sacc[tt][g * 4 + 3] * scale);
                lsum += (p0 + p1) + (p2 + p3);
                ushort4 o4;
                *reinterpret_cast<unsigned*>(&o4.x) = f2bf_pk(p0, p1);
                *reinterpret_cast<unsigned*>(&o4.z) = f2bf_pk(p2, p3);
                int chunk = tt * 4 + g;
                *reinterpret_cast<ushort4*>(pw + l31 * 64 + ((chunk ^ (l31 & 7)) << 3) + h * 4) = o4;
            }
        }
        bf16x8 pb[4];
        #pragma unroll
        for (int step = 0; step < 4; step++)
            pb[step] = *reinterpret_cast<const bf16x8*>(pw + l31 * 64 + (((step * 2 + h) ^ (l31 & 7)) << 3));
        // ---- O^T += V^T P^T ----
        #pragma unroll
        for (int dt = 0; dt < 4; dt++) {
            const unsigned short* vrow = vb + (dt * 32 + l31) * 64;
            #pragma unroll
            for (int step = 0; step < 4; step++) {
                bf16x8 vf = *reinterpret_cast<const bf16x8*>(vrow + (((step * 2 + h) ^ (l31 & 7)) << 3));
                o_acc[dt] = __builtin_amdgcn_mfma_f32_32x32x16_bf16(vf, pb[step], o_acc[dt], 0, 0, 0);
            }
        }
    }
    lsum += __shfl_xor(lsum, 32);

    // ---- write unnormalized partials ----
    float* op = Opart + (size_t)sp * QKV_ELEMS;
    int qrow_g = b * NL + m0 + l31;
    if (lane < 32) lbuf[(size_t)sp * NROWS + qrow_g] = lsum;
    #pragma unroll
    for (int dt = 0; dt < 4; dt++) {
        #pragma unroll
        for (int g = 0; g < 4; g++) {
            f32x4 v4 = { o_acc[dt][g * 4 + 0], o_acc[dt][g * 4 + 1],
                         o_acc[dt][g * 4 + 2], o_acc[dt][g * 4 + 3] };
            *reinterpret_cast<f32x4*>(op + (size_t)qrow_g * ND + dt * 32 + g * 8 + h * 4) = v4;
        }
    }

    // ---- last-arriver merges the group ----
    __syncthreads();                 // drain all waves' stores
    if (threadIdx.x == 0) {
        __threadfence();             // release: flush partials device-wide
        int old = atomicAdd(&cnt[blockIdx.x], 1);
        s_last = (old == NSPLIT - 1);
    }
    __syncthreads();
    if (s_last) {
        __threadfence();             // acquire: invalidate stale cached lines
        int row_local = threadIdx.x >> 1;
        int d0 = (threadIdx.x & 1) * 64;
        int g_row = b * NL + qt * 128 + row_local;
        float L = 0.f;
        #pragma unroll
        for (int s = 0; s < NSPLIT; s++) L += lbuf[(size_t)s * NROWS + g_row];
        float inv = 1.0f / L;
        #pragma unroll
        for (int j = 0; j < 16; j++) {
            float4 a = make_float4(0.f, 0.f, 0.f, 0.f);
            #pragma unroll
            for (int s = 0; s < NSPLIT; s++) {
                float4 o = *reinterpret_cast<const float4*>(Opart + (size_t)s * QKV_ELEMS + (size_t)g_row * ND + d0 + j * 4);
                a.x += o.x; a.y += o.y; a.z += o.z; a.w += o.w;
            }
            float4 res = make_float4(a.x * inv, a.y * inv, a.z * inv, a.w * inv);
            *reinterpret_cast<float4*>(out + (size_t)g_row * ND + d0 + j * 4) = res;
        }
    }
}

extern "C" void kernel_launch(void* const* d_in, const int* in_sizes, int n_in,
                              void* d_out, int out_size, void* d_ws, size_t ws_size,
                              hipStream_t stream) {
    const float* x_inner = (const float*)d_in[0];
    const float* x_outer = (const float*)d_in[1];
    const float* Wq = (const float*)d_in[2];
    const float* bq = (const float*)d_in[3];
    const float* Wk = (const float*)d_in[4];
    const float* bk = (const float*)d_in[5];
    const float* Wv = (const float*)d_in[6];
    const float* bv = (const float*)d_in[7];
    float* out = (float*)d_out;

    // workspace: [ Opart(4x8.4MB) | lbuf ] [ Qb ][ Kb ][ Vtb ][ Wall ][ cnt ]
    size_t union_bytes = 34078720u;
    char* w = (char*)d_ws;
    float* Opart = (float*)w;                                // [4][B*L][D]
    float* lbuf = (float*)(w + (size_t)NSPLIT * QKV_ELEMS * 4);  // [4][B*L]
    unsigned short* Qb = (unsigned short*)(w + union_bytes); // [B,L,D]
    unsigned short* Kb = Qb + QKV_ELEMS;                     // [B,L,D]
    unsigned short* Vtb = Kb + QKV_ELEMS;                    // [B,D,L]
    unsigned short* Wall = Vtb + QKV_ELEMS;                  // [3][D][C]
    int* cnt = (int*)(Wall + 3 * W_ELEMS);                   // [128] group counters

    hipMemsetAsync(cnt, 0, NB * 16 * sizeof(int), stream);
    cast_w3<<<(3 * W_ELEMS + 255) / 256, 256, 0, stream>>>(Wq, Wk, Wv, Wall);
    dim3 pgrid(NB * (NL / 64), 3);
    proj_direct<<<pgrid, 256, 0, stream>>>(x_inner, x_outer, Wall, bq, bk, bv, Qb, Kb, Vtb);
    dim3 fgrid(NB * (NL / 128), NSPLIT);
    flash_attn_split<<<fgrid, 256, 0, stream>>>(Qb, Kb, Vtb, Opart, lbuf, cnt, out, NL / NSPLIT);
}

// Round 11
// 192.742 us; speedup vs baseline: 1.0279x; 1.0279x over previous
//
#include <hip/hip_runtime.h>
#include <hip/hip_bf16.h>

#define NB 8
#define NC 256
#define NL 2048
#define ND 128
#define NROWS (NB * NL)                   // 16384 Q rows
#define QKV_ELEMS ((size_t)NB * NL * ND)  // 2,097,152
#define W_ELEMS (ND * NC)                 // 32,768
#define XS_STRIDE 264                     // 256 + 8 shorts pad: 16B-aligned rows
#define NSPLIT 4

typedef __attribute__((ext_vector_type(8))) short bf16x8;
typedef __attribute__((ext_vector_type(4))) float f32x4;
typedef __attribute__((ext_vector_type(16))) float f32x16;

__device__ __forceinline__ unsigned short f2bf(float f) {
    union { float f; unsigned u; } v; v.f = f;
    unsigned r = v.u + 0x7fffu + ((v.u >> 16) & 1u);
    return (unsigned short)(r >> 16);
}

// packed RNE f32x2 -> bf16x2 (v_cvt_pk_bf16_f32 on gfx950)
__device__ __forceinline__ unsigned f2bf_pk(float a, float b) {
    __hip_bfloat162 h = __float22bfloat162_rn(make_float2(a, b));
    return *reinterpret_cast<unsigned*>(&h);
}

// async global->LDS, 16 B per lane; LDS dest = uniform base + lane*16
__device__ __forceinline__ void load_lds16(const unsigned short* g, unsigned short* l) {
    __builtin_amdgcn_global_load_lds((const __attribute__((address_space(1))) unsigned int*)g,
                                     (__attribute__((address_space(3))) unsigned int*)l, 16, 0, 0);
}

// cast Wq|Wk|Wv -> contiguous bf16 buffer [3][D][C]
__global__ void cast_w3(const float* __restrict__ wq, const float* __restrict__ wk,
                        const float* __restrict__ wv, unsigned short* __restrict__ dst) {
    int i = blockIdx.x * blockDim.x + threadIdx.x;
    if (i >= 3 * W_ELEMS) return;
    int sel = i / W_ELEMS, off = i - sel * W_ELEMS;
    const float* s = (sel == 0) ? wq : (sel == 1) ? wk : wv;
    dst[i] = f2bf(s[off]);
}

// Fused transpose+cast+projection. Reads x [b][C][L] f32 directly.
// blockIdx.x: b*32 + l-tile (64 l's). blockIdx.y: 0 = Q (xi), 1 = K (xo), 2 = V (xo).
__global__ __launch_bounds__(256, 4) void proj_direct(const float* __restrict__ xi,
                                                      const float* __restrict__ xo,
                                                      const unsigned short* __restrict__ Wall,
                                                      const float* __restrict__ bq,
                                                      const float* __restrict__ bk,
                                                      const float* __restrict__ bv,
                                                      unsigned short* __restrict__ Qb,
                                                      unsigned short* __restrict__ Kb,
                                                      unsigned short* __restrict__ Vtb) {
    __shared__ unsigned short xs[64 * XS_STRIDE];  // x^T tile [64 l][256 c] bf16, 33 KB
    int b = blockIdx.x >> 5, lt = blockIdx.x & 31, l0 = lt * 64;
    int y = blockIdx.y;
    int wave = threadIdx.x >> 6, lane = threadIdx.x & 63;
    int ln = lane & 15, quad = lane >> 4;

    // ---- stage: xs[l][c] = bf16(x[c][l0+l]); float4 loads, packed converts ----
    const float* xsrc = (y == 0 ? xi : xo) + (size_t)b * NC * NL + l0;
    int l4 = (lane & 15) * 4;
    int cr0 = wave * 4 + (lane >> 4);
    #pragma unroll
    for (int g = 0; g < 4; g++) {
        float4 r[4];
        #pragma unroll
        for (int gi = 0; gi < 4; gi++) {
            int c = cr0 + (g * 4 + gi) * 16;
            r[gi] = *reinterpret_cast<const float4*>(xsrc + (size_t)c * NL + l4);
        }
        #pragma unroll
        for (int gi = 0; gi < 4; gi++) {
            int c = cr0 + (g * 4 + gi) * 16;
            unsigned pk0 = f2bf_pk(r[gi].x, r[gi].y);
            unsigned pk1 = f2bf_pk(r[gi].z, r[gi].w);
            xs[(l4 + 0) * XS_STRIDE + c] = (unsigned short)pk0;
            xs[(l4 + 1) * XS_STRIDE + c] = (unsigned short)(pk0 >> 16);
            xs[(l4 + 2) * XS_STRIDE + c] = (unsigned short)pk1;
            xs[(l4 + 3) * XS_STRIDE + c] = (unsigned short)(pk1 >> 16);
        }
    }
    __syncthreads();

    if (y < 2) {
        // ---- Q or K: out[l][d] = sum_c xs[l][c] * W[d][c] + bias[d], [B,L,D] ----
        const unsigned short* Wb = Wall + (size_t)y * W_ELEMS;
        const float* bias = y ? bk : bq;
        unsigned short* out = y ? Kb : Qb;
        int m0w = wave * 16;
        f32x4 acc[8] = {};
        #pragma unroll
        for (int s = 0; s < 8; s++) {
            bf16x8 af = *reinterpret_cast<const bf16x8*>(xs + (m0w + ln) * XS_STRIDE + s * 32 + quad * 8);
            #pragma unroll
            for (int t = 0; t < 8; t++) {
                bf16x8 bfr = *reinterpret_cast<const bf16x8*>(Wb + (size_t)(t * 16 + ln) * NC + s * 32 + quad * 8);
                acc[t] = __builtin_amdgcn_mfma_f32_16x16x32_bf16(af, bfr, acc[t], 0, 0, 0);
            }
        }
        #pragma unroll
        for (int t = 0; t < 8; t++) {
            int col = t * 16 + ln;
            float bi = bias[col];
            unsigned pk0 = f2bf_pk(acc[t][0] + bi, acc[t][1] + bi);
            unsigned pk1 = f2bf_pk(acc[t][2] + bi, acc[t][3] + bi);
            size_t base = (size_t)(b * NL + l0 + m0w + quad * 4) * ND + col;
            out[base + 0 * ND] = (unsigned short)pk0;
            out[base + 1 * ND] = (unsigned short)(pk0 >> 16);
            out[base + 2 * ND] = (unsigned short)pk1;
            out[base + 3 * ND] = (unsigned short)(pk1 >> 16);
        }
    } else {
        // ---- V: vt[d][l] = sum_c W[d][c]*xs[l][c] + bv[d], [B,D,L] ----
        const unsigned short* Wb = Wall + 2 * (size_t)W_ELEMS;
        f32x4 acc[2][4] = {};
        #pragma unroll
        for (int s = 0; s < 8; s++) {
            bf16x8 wf0 = *reinterpret_cast<const bf16x8*>(Wb + (size_t)(wave * 32 + ln) * NC + s * 32 + quad * 8);
            bf16x8 wf1 = *reinterpret_cast<const bf16x8*>(Wb + (size_t)(wave * 32 + 16 + ln) * NC + s * 32 + quad * 8);
            #pragma unroll
            for (int t = 0; t < 4; t++) {
                bf16x8 xb = *reinterpret_cast<const bf16x8*>(xs + (t * 16 + ln) * XS_STRIDE + s * 32 + quad * 8);
                acc[0][t] = __builtin_amdgcn_mfma_f32_16x16x32_bf16(wf0, xb, acc[0][t], 0, 0, 0);
                acc[1][t] = __builtin_amdgcn_mfma_f32_16x16x32_bf16(wf1, xb, acc[1][t], 0, 0, 0);
            }
        }
        #pragma unroll
        for (int u = 0; u < 2; u++)
            #pragma unroll
            for (int t = 0; t < 4; t++)
                #pragma unroll
                for (int r = 0; r < 4; r++) {
                    int d = wave * 32 + u * 16 + quad * 4 + r;
                    Vtb[(size_t)(b * ND + d) * NL + l0 + t * 16 + ln] = f2bf(acc[u][t][r] + bv[d]);
                }
    }
}

// split-KV flash attention, 32x32 MFMA, 128-q blocks, fixed-M softmax, double-buffered K/V,
// fused last-block merge. LDS = exactly 81,920 B -> 2 blocks/CU (the R10 regression was
// +512 B from a dedicated shared flag; the flag now reuses pbuf, dead after the K-loop).
__global__ __launch_bounds__(256, 2) void flash_attn_split(const unsigned short* __restrict__ Q,
                                                           const unsigned short* __restrict__ K,
                                                           const unsigned short* __restrict__ Vt,
                                                           float* __restrict__ Opart,
                                                           float* __restrict__ lbuf,
                                                           int* __restrict__ cnt,
                                                           float* __restrict__ out,
                                                           int kvlen) {
    __shared__ unsigned short kbuf[2][64 * 128];   // 32 KB
    __shared__ unsigned short vbuf[2][128 * 64];   // 32 KB
    __shared__ unsigned short pbuf[4][32 * 64];    // 16 KB; reused as merge flag after loop
    int b = blockIdx.x >> 4, qt = blockIdx.x & 15;
    int sp = blockIdx.y;
    int kv0 = sp * kvlen;
    int wave = threadIdx.x >> 6, lane = threadIdx.x & 63;
    int l31 = lane & 31, h = lane >> 5;
    int m0 = qt * 128 + wave * 32;
    const float scale = 0.08838834764831845f * 1.4426950408889634f;  // 1/sqrt(128) * log2(e)

    bf16x8 qf[8];
    const unsigned short* qrow = Q + (size_t)(b * NL + m0 + l31) * ND + h * 8;
    #pragma unroll
    for (int s = 0; s < 8; s++) qf[s] = *reinterpret_cast<const bf16x8*>(qrow + s * 16);

    float lsum = 0.f;
    f32x16 o_acc[4] = {};

    unsigned short* pw = pbuf[wave];
    const unsigned short* kg = K + (size_t)b * NL * ND;
    const unsigned short* vg = Vt + (size_t)b * ND * NL;

    int krt = wave * 16 + (lane >> 4);
    int kjs = (lane & 15);
    int vdt = wave * 32 + (lane >> 3);
    int vjs = (lane & 7);

    // ---- prefetch tile 0 into buffer 0 ----
    {
        int kt = kv0;
        #pragma unroll
        for (int i = 0; i < 4; i++) {
            int rt = krt + i * 4;
            load_lds16(kg + (size_t)(kt + rt) * ND + (kjs ^ (rt & 15)) * 8, kbuf[0] + (wave * 16 + i * 4) * 128);
        }
        #pragma unroll
        for (int i = 0; i < 4; i++) {
            int dt = vdt + i * 8;
            load_lds16(vg + (size_t)dt * NL + kt + (vjs ^ (dt & 7)) * 8, vbuf[0] + (wave * 32 + i * 8) * 64);
        }
    }

    int niter = kvlen >> 6;
    for (int it = 0; it < niter; it++) {
        int cur = it & 1;
        __syncthreads();  // vmcnt drain + barrier: buffer `cur` ready, `cur^1` free

        if (it + 1 < niter) {
            int kt = kv0 + (it + 1) * 64;
            int nxt = cur ^ 1;
            #pragma unroll
            for (int i = 0; i < 4; i++) {
                int rt = krt + i * 4;
                load_lds16(kg + (size_t)(kt + rt) * ND + (kjs ^ (rt & 15)) * 8, kbuf[nxt] + (wave * 16 + i * 4) * 128);
            }
            #pragma unroll
            for (int i = 0; i < 4; i++) {
                int dt = vdt + i * 8;
                load_lds16(vg + (size_t)dt * NL + kt + (vjs ^ (dt & 7)) * 8, vbuf[nxt] + (wave * 32 + i * 8) * 64);
            }
        }
        const unsigned short* kb = kbuf[cur];
        const unsigned short* vb = vbuf[cur];

        // ---- S^T = K Q^T ----
        f32x16 sacc[2] = {};
        #pragma unroll
        for (int tt = 0; tt < 2; tt++) {
            const unsigned short* krow_p = kb + (tt * 32 + l31) * 128;
            #pragma unroll
            for (int s = 0; s < 8; s++) {
                bf16x8 kf = *reinterpret_cast<const bf16x8*>(krow_p + (((s * 2 + h) ^ (lane & 15)) << 3));
                sacc[tt] = __builtin_amdgcn_mfma_f32_32x32x16_bf16(kf, qf[s], sacc[tt], 0, 0, 0);
            }
        }
        // ---- fixed-M softmax + packed P^T write ----
        #pragma unroll
        for (int tt = 0; tt < 2; tt++) {
            #pragma unroll
            for (int g = 0; g < 4; g++) {
                float p0 = __builtin_exp2f(sacc[tt][g * 4 + 0] * scale);
                float p1 = __builtin_exp2f(sacc[tt][g * 4 + 1] * scale);
                float p2 = __builtin_exp2f(sacc[tt][g * 4 + 2] * scale);
                float p3 = __builtin_exp2f(sacc[tt][g * 4 + 3] * scale);
                lsum += (p0 + p1) + (p2 + p3);
                ushort4 o4;
                *reinterpret_cast<unsigned*>(&o4.x) = f2bf_pk(p0, p1);
                *reinterpret_cast<unsigned*>(&o4.z) = f2bf_pk(p2, p3);
                int chunk = tt * 4 + g;
                *reinterpret_cast<ushort4*>(pw + l31 * 64 + ((chunk ^ (l31 & 7)) << 3) + h * 4) = o4;
            }
        }
        bf16x8 pb[4];
        #pragma unroll
        for (int step = 0; step < 4; step++)
            pb[step] = *reinterpret_cast<const bf16x8*>(pw + l31 * 64 + (((step * 2 + h) ^ (l31 & 7)) << 3));
        // ---- O^T += V^T P^T ----
        #pragma unroll
        for (int dt = 0; dt < 4; dt++) {
            const unsigned short* vrow = vb + (dt * 32 + l31) * 64;
            #pragma unroll
            for (int step = 0; step < 4; step++) {
                bf16x8 vf = *reinterpret_cast<const bf16x8*>(vrow + (((step * 2 + h) ^ (l31 & 7)) << 3));
                o_acc[dt] = __builtin_amdgcn_mfma_f32_32x32x16_bf16(vf, pb[step], o_acc[dt], 0, 0, 0);
            }
        }
    }
    lsum += __shfl_xor(lsum, 32);

    // ---- write unnormalized partials ----
    float* op = Opart + (size_t)sp * QKV_ELEMS;
    int qrow_g = b * NL + m0 + l31;
    if (lane < 32) lbuf[(size_t)sp * NROWS + qrow_g] = lsum;
    #pragma unroll
    for (int dt = 0; dt < 4; dt++) {
        #pragma unroll
        for (int g = 0; g < 4; g++) {
            f32x4 v4 = { o_acc[dt][g * 4 + 0], o_acc[dt][g * 4 + 1],
                         o_acc[dt][g * 4 + 2], o_acc[dt][g * 4 + 3] };
            *reinterpret_cast<f32x4*>(op + (size_t)qrow_g * ND + dt * 32 + g * 8 + h * 4) = v4;
        }
    }

    // ---- last-arriver merges the group (flag lives in pbuf, dead after K-loop) ----
    volatile int* flag = reinterpret_cast<volatile int*>(&pbuf[0][0]);
    __syncthreads();                 // drain all waves' partial stores + pbuf reads done
    if (threadIdx.x == 0) {
        __threadfence();             // release: flush partials device-wide
        int old = atomicAdd(&cnt[blockIdx.x], 1);
        *flag = (old == NSPLIT - 1);
    }
    __syncthreads();
    if (*flag) {
        __threadfence();             // acquire: invalidate stale cached lines
        int row_local = threadIdx.x >> 1;
        int d0 = (threadIdx.x & 1) * 64;
        int g_row = b * NL + qt * 128 + row_local;
        float L = 0.f;
        #pragma unroll
        for (int s = 0; s < NSPLIT; s++) L += lbuf[(size_t)s * NROWS + g_row];
        float inv = 1.0f / L;
        #pragma unroll
        for (int j = 0; j < 16; j++) {
            float4 a = make_float4(0.f, 0.f, 0.f, 0.f);
            #pragma unroll
            for (int s = 0; s < NSPLIT; s++) {
                float4 o = *reinterpret_cast<const float4*>(Opart + (size_t)s * QKV_ELEMS + (size_t)g_row * ND + d0 + j * 4);
                a.x += o.x; a.y += o.y; a.z += o.z; a.w += o.w;
            }
            float4 res = make_float4(a.x * inv, a.y * inv, a.z * inv, a.w * inv);
            *reinterpret_cast<float4*>(out + (size_t)g_row * ND + d0 + j * 4) = res;
        }
    }
}

extern "C" void kernel_launch(void* const* d_in, const int* in_sizes, int n_in,
                              void* d_out, int out_size, void* d_ws, size_t ws_size,
                              hipStream_t stream) {
    const float* x_inner = (const float*)d_in[0];
    const float* x_outer = (const float*)d_in[1];
    const float* Wq = (const float*)d_in[2];
    const float* bq = (const float*)d_in[3];
    const float* Wk = (const float*)d_in[4];
    const float* bk = (const float*)d_in[5];
    const float* Wv = (const float*)d_in[6];
    const float* bv = (const float*)d_in[7];
    float* out = (float*)d_out;

    // workspace: [ Opart(4x8.4MB) | lbuf ] [ Qb ][ Kb ][ Vtb ][ Wall ][ cnt ]
    size_t union_bytes = 34078720u;
    char* w = (char*)d_ws;
    float* Opart = (float*)w;                                // [4][B*L][D]
    float* lbuf = (float*)(w + (size_t)NSPLIT * QKV_ELEMS * 4);  // [4][B*L]
    unsigned short* Qb = (unsigned short*)(w + union_bytes); // [B,L,D]
    unsigned short* Kb = Qb + QKV_ELEMS;                     // [B,L,D]
    unsigned short* Vtb = Kb + QKV_ELEMS;                    // [B,D,L]
    unsigned short* Wall = Vtb + QKV_ELEMS;                  // [3][D][C]
    int* cnt = (int*)(Wall + 3 * W_ELEMS);                   // [128] group counters

    hipMemsetAsync(cnt, 0, NB * 16 * sizeof(int), stream);
    cast_w3<<<(3 * W_ELEMS + 255) / 256, 256, 0, stream>>>(Wq, Wk, Wv, Wall);
    dim3 pgrid(NB * (NL / 64), 3);
    proj_direct<<<pgrid, 256, 0, stream>>>(x_inner, x_outer, Wall, bq, bk, bv, Qb, Kb, Vtb);
    dim3 fgrid(NB * (NL / 128), NSPLIT);
    flash_attn_split<<<fgrid, 256, 0, stream>>>(Qb, Kb, Vtb, Opart, lbuf, cnt, out, NL / NSPLIT);
}